// Round 4
// baseline (393.637 us; speedup 1.0000x reference)
//
#include <hip/hip_runtime.h>
#include <stdint.h>

#define NN 6144        // nodes
#define NC 576         // padded V columns (517 used)

typedef __bf16 bf16x8 __attribute__((ext_vector_type(8)));
typedef float  f32x4  __attribute__((ext_vector_type(4)));

__device__ __forceinline__ unsigned short f2bf(float f) {
  unsigned u = __float_as_uint(f);
  u += 0x7FFFu + ((u >> 16) & 1u);   // RNE
  return (unsigned short)(u >> 16);
}

__device__ __forceinline__ void async_load16(const void* g, void* l) {
  __builtin_amdgcn_global_load_lds(
      (__attribute__((address_space(1))) void*)(uintptr_t)g,
      (__attribute__((address_space(3))) void*)(uint32_t)(uintptr_t)l,
      16, 0, 0);
}

// ---------------- Kernel 0: adj int32 -> bf16 (0/1) prepass; also zero T ----------------
__global__ __launch_bounds__(256) void k0_pack(
    const int* __restrict__ adj, unsigned short* __restrict__ Abf,
    float* __restrict__ T)
{
  if (blockIdx.x == 0 && threadIdx.x < 256) T[threadIdx.x] = 0.f;
  const size_t total8 = (size_t)NN * NN / 8;
  const int4* a4 = (const int4*)adj;
  uint4* o4 = (uint4*)Abf;
  for (size_t g = (size_t)blockIdx.x * 256 + threadIdx.x; g < total8;
       g += (size_t)gridDim.x * 256) {
    int4 qa = a4[2 * g], qb = a4[2 * g + 1];
    uint4 p;
    p.x = (unsigned)qa.x * 0x3F80u | (unsigned)qa.y * 0x3F800000u;
    p.y = (unsigned)qa.z * 0x3F80u | (unsigned)qa.w * 0x3F800000u;
    p.z = (unsigned)qb.x * 0x3F80u | (unsigned)qb.y * 0x3F800000u;
    p.w = (unsigned)qb.z * 0x3F80u | (unsigned)qb.w * 0x3F800000u;
    o4[g] = p;
  }
}

// ---------------- Kernel 1: features, score exponentials, V (bf16 col-major), T ----------------
// grid 384 x 256 thr; block handles 16 nodes (R2's verified structure, split 2x for occupancy).
__global__ __launch_bounds__(256) void k1_feat(
    const float* __restrict__ x, const float* __restrict__ W,
    const float* __restrict__ Wb, const float* __restrict__ Aw,
    const float* __restrict__ Ab, unsigned short* __restrict__ Vcm,
    float* __restrict__ e_src, float* __restrict__ T)
{
  __shared__ float xs[256][16];     // xs[k][n]
  __shared__ float hl[16][257];
  __shared__ float sdste[4][16];
  const int t  = threadIdx.x;
  const int nb = blockIdx.x * 16;

  { // stage x: 16 threads per node, 16 k's each
    const int n = t >> 4, kq = (t & 15) * 16;
    const float4* xp = (const float4*)(x + (size_t)(nb + n) * 256 + kq);
#pragma unroll
    for (int j = 0; j < 4; ++j) {
      float4 v = xp[j];
      int k = kq + j * 4;
      xs[k][n] = v.x; xs[k+1][n] = v.y; xs[k+2][n] = v.z; xs[k+3][n] = v.w;
    }
  }
  __syncthreads();

  const int cg = t & 31, ng = t >> 5;      // 8 cols x 2 nodes per thread
  const int c0 = cg * 8, h = c0 >> 6, d0 = c0 & 63;
  const float* wp = W + h * 16384 + d0;
  float acc[2][8];
#pragma unroll
  for (int i = 0; i < 2; ++i)
#pragma unroll
    for (int j = 0; j < 8; ++j) acc[i][j] = 0.f;

#pragma unroll 4
  for (int k = 0; k < 256; ++k) {
    float4 wa = *(const float4*)(wp + (size_t)k * 64);
    float4 wb = *(const float4*)(wp + (size_t)k * 64 + 4);
    float2 xa = *(const float2*)(&xs[k][ng * 2]);
    float xr[2] = {xa.x, xa.y};
    float wr[8] = {wa.x, wa.y, wa.z, wa.w, wb.x, wb.y, wb.z, wb.w};
#pragma unroll
    for (int i = 0; i < 2; ++i)
#pragma unroll
      for (int j = 0; j < 8; ++j) acc[i][j] += xr[i] * wr[j];
  }
#pragma unroll
  for (int i = 0; i < 2; ++i)
#pragma unroll
    for (int j = 0; j < 8; ++j)
      hl[ng * 2 + i][c0 + j] = acc[i][j] + Wb[c0 + j];
  __syncthreads();

  if (t < 64) { // (node, head) attention dots: 16 nodes x 4 heads
    const int node = t & 15, hd = t >> 4;
    float ss = Ab[hd], sd = 0.f;
#pragma unroll 8
    for (int d = 0; d < 64; ++d) {
      float hv = hl[node][hd * 64 + d];
      ss += hv * Aw[hd * 128 + d];
      sd += hv * Aw[hd * 128 + 64 + d];
    }
    e_src[hd * NN + nb + node] = expf(ss);
    sdste[hd][node] = expf(sd);
  }
  { // T partial (col t)
    float s = 0.f;
#pragma unroll 8
    for (int n2 = 0; n2 < 16; ++n2) s += hl[n2][t];
    atomicAdd(&T[t], s);
  }
  __syncthreads();

  { // write V column-major bf16: 16 groups x 36 cols
    const int n = t & 15, q = t >> 4;
    for (int cc = 0; cc < 36; ++cc) {
      int col = q * 36 + cc;
      float val;
      if (col < 512) {
        int hh = col >> 7, rem = col & 127, d = rem & 63;
        float hv = hl[n][hh * 64 + d];
        val = (rem < 64) ? sdste[hh][n] * hv : hv;
      } else if (col < 516) val = sdste[col - 512][n];
      else if (col == 516)  val = 1.0f;
      else                  val = 0.0f;
      Vcm[(size_t)col * NN + nb + n] = f2bf(val);
    }
  }
}

// ---------------- Kernel 2: out2[ks] = Abf @ V, pure-async (m97 structure) ----------------
// tile 96x288, BK=64, grid = cb(2) x ks(nks) x rb(64); nks=6 -> 768 blocks = 3/CU.
// 4 waves 2x2, wave tile 48x144 (mt3 x nt9). LDS 48 KB, XOR-swizzled granules.
__global__ __launch_bounds__(256, 3) void k2_gemm(
    const unsigned short* __restrict__ Abf, const unsigned short* __restrict__ Vcm,
    float* __restrict__ out2, int nks)
{
  __shared__ unsigned short lA[96 * 64];   // 12,288 B
  __shared__ unsigned short lB[288 * 64];  // 36,864 B
  const int t   = threadIdx.x;
  const int bid = blockIdx.x;
  const int rb  = bid & 63;
  const int tmp = bid >> 6;
  const int ks  = tmp % nks;
  const int cb  = tmp / nks;
  const int krange = NN / nks;
  const int i0 = rb * 96, n0 = cb * 288, k0 = ks * krange;
  const int w = t >> 6, l = t & 63;
  const int wm = w & 1, wn = w >> 1;
  const int lm = l & 15, lk = l >> 4;

  f32x4 acc[3][9];
#pragma unroll
  for (int mt = 0; mt < 3; ++mt)
#pragma unroll
    for (int nt = 0; nt < 9; ++nt) acc[mt][nt] = (f32x4){0.f, 0.f, 0.f, 0.f};

  const int iters = krange / 64;
  for (int it = 0; it < iters; ++it) {
    const int kb = k0 + it * 64;
    { // A: 96x64 bf16 = 768 granules, 3/thread
#pragma unroll
      for (int u = 0; u < 3; ++u) {
        const int gi0 = w * 192 + u * 64;
        const int gi  = gi0 + l;
        const int row = gi >> 3, gsl = gi & 7;
        const int gsrc = gsl ^ (row & 7);
        async_load16(Abf + (size_t)(i0 + row) * NN + kb + gsrc * 8,
                     (char*)lA + (size_t)gi0 * 16);
      }
    }
    { // B: 288x64 bf16 = 2304 granules, 9/thread
#pragma unroll
      for (int u = 0; u < 9; ++u) {
        const int gi0 = w * 576 + u * 64;
        const int gi  = gi0 + l;
        const int col = gi >> 3, gsl = gi & 7;
        const int gsrc = gsl ^ (col & 7);
        async_load16(Vcm + (size_t)(n0 + col) * NN + kb + gsrc * 8,
                     (char*)lB + (size_t)gi0 * 16);
      }
    }
    __syncthreads();
#pragma unroll
    for (int ks2 = 0; ks2 < 2; ++ks2) {
      const int kgo = ks2 * 4 + lk;
      bf16x8 afrag[3];
#pragma unroll
      for (int mt = 0; mt < 3; ++mt) {
        const int rr = wm * 48 + mt * 16 + lm;
        afrag[mt] = *(const bf16x8*)((const char*)lA + (size_t)rr * 128 + ((kgo ^ (rr & 7)) * 16));
      }
#pragma unroll
      for (int nt = 0; nt < 9; ++nt) {
        const int cc = wn * 144 + nt * 16 + lm;
        bf16x8 b = *(const bf16x8*)((const char*)lB + (size_t)cc * 128 + ((kgo ^ (cc & 7)) * 16));
#pragma unroll
        for (int mt = 0; mt < 3; ++mt)
          acc[mt][nt] = __builtin_amdgcn_mfma_f32_16x16x32_bf16(afrag[mt], b, acc[mt][nt], 0, 0, 0);
      }
    }
    __syncthreads();
  }

  float* o = out2 + (size_t)ks * ((size_t)NN * NC);
  const int row0 = i0 + wm * 48 + (l >> 4) * 4;
  const int colb = n0 + wn * 144 + (l & 15);
#pragma unroll
  for (int mt = 0; mt < 3; ++mt)
#pragma unroll
    for (int nt = 0; nt < 9; ++nt)
#pragma unroll
      for (int rr = 0; rr < 4; ++rr)
        o[(size_t)(row0 + mt * 16 + rr) * NC + colb + nt * 16] = acc[mt][nt][rr];
}

// ---------------- Kernel 2 legacy (in-kernel convert, small-ws fallback) ----------------
__global__ __launch_bounds__(256, 3) void k2_legacy(
    const int* __restrict__ adj, const unsigned short* __restrict__ Vcm,
    float* __restrict__ out2, int nks)
{
  __shared__ unsigned short lA[128 * 64];
  __shared__ unsigned short lB[192 * 64];
  const int t   = threadIdx.x;
  const int bid = blockIdx.x;
  const int rb  = bid % 48;
  const int tmp = bid / 48;
  const int ks  = tmp % nks;
  const int cb  = tmp / nks;
  const int krange = NN / nks;
  const int i0 = rb * 128, n0 = cb * 192, k0 = ks * krange;
  const int w = t >> 6, l = t & 63;
  const int wm = w & 1, wn = w >> 1;
  const int lm = l & 15, lk = l >> 4;
  const int r  = t >> 1, cq = t & 1;

  f32x4 acc[4][6];
#pragma unroll
  for (int mt = 0; mt < 4; ++mt)
#pragma unroll
    for (int nt = 0; nt < 6; ++nt) acc[mt][nt] = (f32x4){0.f, 0.f, 0.f, 0.f};

  const int iters = krange / 64;
  for (int it = 0; it < iters; ++it) {
    const int kb = k0 + it * 64;
    {
      const int4* ap = (const int4*)(adj + (size_t)(i0 + r) * NN + kb + cq * 32);
#pragma unroll
      for (int g = 0; g < 4; ++g) {
        int4 qa = ap[2 * g], qb = ap[2 * g + 1];
        uint4 p;
        p.x = (unsigned)qa.x * 0x3F80u | (unsigned)qa.y * 0x3F800000u;
        p.y = (unsigned)qa.z * 0x3F80u | (unsigned)qa.w * 0x3F800000u;
        p.z = (unsigned)qb.x * 0x3F80u | (unsigned)qb.y * 0x3F800000u;
        p.w = (unsigned)qb.z * 0x3F80u | (unsigned)qb.w * 0x3F800000u;
        const int gran = cq * 4 + g;
        *(uint4*)(&lA[r * 64 + ((gran ^ (r & 7)) * 8)]) = p;
      }
    }
    {
      const int clbase = w * 48;
      const int crow = l >> 3, j = l & 7;
#pragma unroll
      for (int u = 0; u < 6; ++u) {
        int cl = clbase + u * 8 + crow;
        int g = j ^ (cl & 7);
        async_load16(Vcm + (size_t)(n0 + cl) * NN + kb + g * 8,
                     (char*)lB + (size_t)(clbase + u * 8) * 128);
      }
    }
    __syncthreads();
#pragma unroll
    for (int ks2 = 0; ks2 < 2; ++ks2) {
      const int kgo = ks2 * 4 + lk;
      bf16x8 afrag[4];
#pragma unroll
      for (int mt = 0; mt < 4; ++mt) {
        const int rr = wm * 64 + mt * 16 + lm;
        afrag[mt] = *(const bf16x8*)(&lA[rr * 64 + ((kgo ^ (rr & 7)) * 8)]);
      }
#pragma unroll
      for (int nt = 0; nt < 6; ++nt) {
        bf16x8 b = *(const bf16x8*)(&lB[(wn * 96 + nt * 16 + lm) * 64 + ((kgo ^ (lm & 7)) * 8)]);
#pragma unroll
        for (int mt = 0; mt < 4; ++mt)
          acc[mt][nt] = __builtin_amdgcn_mfma_f32_16x16x32_bf16(afrag[mt], b, acc[mt][nt], 0, 0, 0);
      }
    }
    __syncthreads();
  }

  float* o = out2 + (size_t)ks * ((size_t)NN * NC);
  const int row0 = i0 + wm * 64 + (l >> 4) * 4;
  const int colb = n0 + wn * 96 + (l & 15);
#pragma unroll
  for (int mt = 0; mt < 4; ++mt)
#pragma unroll
    for (int nt = 0; nt < 6; ++nt)
#pragma unroll
      for (int rr = 0; rr < 4; ++rr)
        o[(size_t)(row0 + mt * 16 + rr) * NC + colb + nt * 16] = acc[mt][nt][rr];
}

// ---------------- Kernel 3: combine across nks K-partials ----------------
__global__ __launch_bounds__(256) void k3_final(
    const float* __restrict__ out2, const float* __restrict__ e_src,
    const float* __restrict__ T, float* __restrict__ out, int nks)
{
  const int n = blockIdx.x, c = threadIdx.x;
  const int h = c >> 6, d = c & 63;
  float Se = 0.f, Sp = 0.f, E = 0.f, dg = 0.f;
  for (int s = 0; s < nks; ++s) {
    const float* ra = out2 + (size_t)s * ((size_t)NN * NC) + (size_t)n * NC;
    Se += ra[h * 128 + d];
    Sp += ra[h * 128 + 64 + d];
    E  += ra[512 + h];
    dg += ra[516];
  }
  float e = e_src[h * NN + n];
  float D = e * E + ((float)NN - dg);
  out[(size_t)n * 256 + c] = (e * Se + (T[c] - Sp)) / D;
}

extern "C" void kernel_launch(void* const* d_in, const int* in_sizes, int n_in,
                              void* d_out, int out_size, void* d_ws, size_t ws_size,
                              hipStream_t stream) {
  const float* x  = (const float*)d_in[0];
  const int*   adj= (const int*)d_in[1];
  const float* W  = (const float*)d_in[2];
  const float* Wb = (const float*)d_in[3];
  const float* Aw = (const float*)d_in[4];
  const float* Ab = (const float*)d_in[5];
  float* out = (float*)d_out;
  char* ws = (char*)d_ws;
  unsigned short* Vcm = (unsigned short*)ws;            // 7,077,888 B
  float* e_src = (float*)(ws + 7077888);                // 98,304 B
  float* T     = (float*)(ws + 7176192);                // 1,024 B
  unsigned short* Abf = (unsigned short*)(ws + 7177216);// 75,497,472 B
  float* out2A = (float*)(ws + 82674688);               // nks x 14,155,776 B
  float* out2L = (float*)(ws + 7177216);                // legacy overlays Abf

  const size_t slab = (size_t)NN * NC * 4;
  const size_t asyncBase = 82674688;

  if (ws_size >= asyncBase + 2 * slab) {
    int nks = 2;
    if (ws_size >= asyncBase + 6 * slab)      nks = 6;  // grid 768 = 3 blk/CU
    else if (ws_size >= asyncBase + 4 * slab) nks = 4;
    hipLaunchKernelGGL(k0_pack, dim3(2048), dim3(256), 0, stream, adj, Abf, T);
    hipLaunchKernelGGL(k1_feat, dim3(384), dim3(256), 0, stream, x, W, Wb, Aw, Ab, Vcm, e_src, T);
    hipLaunchKernelGGL(k2_gemm, dim3(64 * 2 * nks), dim3(256), 0, stream, Abf, Vcm, out2A, nks);
    hipLaunchKernelGGL(k3_final, dim3(NN), dim3(256), 0, stream, out2A, e_src, T, out, nks);
  } else {
    int nks = (ws_size >= 7177216 + 4 * slab) ? 4 : 2;
    hipMemsetAsync(T, 0, 1024, stream);
    hipLaunchKernelGGL(k1_feat, dim3(384), dim3(256), 0, stream, x, W, Wb, Aw, Ab, Vcm, e_src, T);
    hipLaunchKernelGGL(k2_legacy, dim3(48 * 3 * nks), dim3(256), 0, stream, adj, Vcm, out2L, nks);
    hipLaunchKernelGGL(k3_final, dim3(NN), dim3(256), 0, stream, out2L, e_src, T, out, nks);
  }
}

// Round 5
// 340.727 us; speedup vs baseline: 1.1553x; 1.1553x over previous
//
#include <hip/hip_runtime.h>
#include <stdint.h>

#define NN 6144        // nodes
#define NC 576         // padded V columns (517 used)

typedef float f32x4 __attribute__((ext_vector_type(4)));

// f32 -> OCP e4m3fn, RNE, clamp to +-448
__device__ __forceinline__ unsigned char f2e4m3(float f) {
  unsigned u = __float_as_uint(f);
  unsigned sgn = (u >> 24) & 0x80u;
  unsigned au = u & 0x7FFFFFFFu;
  if (au >= 0x43E00000u) return (unsigned char)(sgn | 0x7E);   // >= 448
  if (au < 0x3C800000u) {                                      // < 2^-6: subnormal
    int q = (int)rintf(__uint_as_float(au) * 512.0f);          // step 2^-9
    return (unsigned char)(sgn | (q >= 8 ? 0x08 : q));
  }
  unsigned r = au + 0x7FFFFu + ((au >> 20) & 1u);              // RNE to 3 mantissa bits
  int e = (int)(r >> 23) - 127;
  unsigned m = (r >> 20) & 7u;
  return (unsigned char)(sgn | ((unsigned)(e + 7) << 3) | m);
}

__device__ __forceinline__ void async_load16(const void* g, void* l) {
  __builtin_amdgcn_global_load_lds(
      (__attribute__((address_space(1))) void*)(uintptr_t)g,
      (__attribute__((address_space(3))) void*)(uint32_t)(uintptr_t)l,
      16, 0, 0);
}

// ---------------- Kernel 0: adj int32 -> fp8 e4m3 (0x00 / 0x38 = 1.0); zero T ----------------
__global__ __launch_bounds__(256) void k0_pack(
    const int* __restrict__ adj, unsigned char* __restrict__ A8,
    float* __restrict__ T)
{
  if (blockIdx.x == 0 && threadIdx.x < 256) T[threadIdx.x] = 0.f;
  const size_t total8 = (size_t)NN * NN / 8;   // 8 ints -> 8 bytes
  const int4* a4 = (const int4*)adj;
  uint2* o2 = (uint2*)A8;
  for (size_t g = (size_t)blockIdx.x * 256 + threadIdx.x; g < total8;
       g += (size_t)gridDim.x * 256) {
    int4 qa = a4[2 * g], qb = a4[2 * g + 1];
    uint2 p;
    p.x = (unsigned)qa.x * 0x38u | (unsigned)qa.y * 0x3800u |
          (unsigned)qa.z * 0x380000u | (unsigned)qa.w * 0x38000000u;
    p.y = (unsigned)qb.x * 0x38u | (unsigned)qb.y * 0x3800u |
          (unsigned)qb.z * 0x380000u | (unsigned)qb.w * 0x38000000u;
    o2[g] = p;
  }
}

// ---------------- Kernel 1: features, score exponentials, V (fp8 col-major), T ----------------
// grid 384 x 256 thr; block handles 16 nodes (R4 structure; only V dtype changed).
__global__ __launch_bounds__(256) void k1_feat(
    const float* __restrict__ x, const float* __restrict__ W,
    const float* __restrict__ Wb, const float* __restrict__ Aw,
    const float* __restrict__ Ab, unsigned char* __restrict__ V8,
    float* __restrict__ e_src, float* __restrict__ T)
{
  __shared__ float xs[256][16];
  __shared__ float hl[16][257];
  __shared__ float sdste[4][16];
  const int t  = threadIdx.x;
  const int nb = blockIdx.x * 16;

  {
    const int n = t >> 4, kq = (t & 15) * 16;
    const float4* xp = (const float4*)(x + (size_t)(nb + n) * 256 + kq);
#pragma unroll
    for (int j = 0; j < 4; ++j) {
      float4 v = xp[j];
      int k = kq + j * 4;
      xs[k][n] = v.x; xs[k+1][n] = v.y; xs[k+2][n] = v.z; xs[k+3][n] = v.w;
    }
  }
  __syncthreads();

  const int cg = t & 31, ng = t >> 5;
  const int c0 = cg * 8, h = c0 >> 6, d0 = c0 & 63;
  const float* wp = W + h * 16384 + d0;
  float acc[2][8];
#pragma unroll
  for (int i = 0; i < 2; ++i)
#pragma unroll
    for (int j = 0; j < 8; ++j) acc[i][j] = 0.f;

#pragma unroll 4
  for (int k = 0; k < 256; ++k) {
    float4 wa = *(const float4*)(wp + (size_t)k * 64);
    float4 wb = *(const float4*)(wp + (size_t)k * 64 + 4);
    float2 xa = *(const float2*)(&xs[k][ng * 2]);
    float xr[2] = {xa.x, xa.y};
    float wr[8] = {wa.x, wa.y, wa.z, wa.w, wb.x, wb.y, wb.z, wb.w};
#pragma unroll
    for (int i = 0; i < 2; ++i)
#pragma unroll
      for (int j = 0; j < 8; ++j) acc[i][j] += xr[i] * wr[j];
  }
#pragma unroll
  for (int i = 0; i < 2; ++i)
#pragma unroll
    for (int j = 0; j < 8; ++j)
      hl[ng * 2 + i][c0 + j] = acc[i][j] + Wb[c0 + j];
  __syncthreads();

  if (t < 64) {
    const int node = t & 15, hd = t >> 4;
    float ss = Ab[hd], sd = 0.f;
#pragma unroll 8
    for (int d = 0; d < 64; ++d) {
      float hv = hl[node][hd * 64 + d];
      ss += hv * Aw[hd * 128 + d];
      sd += hv * Aw[hd * 128 + 64 + d];
    }
    e_src[hd * NN + nb + node] = expf(ss);
    sdste[hd][node] = expf(sd);
  }
  {
    float s = 0.f;
#pragma unroll 8
    for (int n2 = 0; n2 < 16; ++n2) s += hl[n2][t];
    atomicAdd(&T[t], s);
  }
  __syncthreads();

  { // write V column-major fp8: 16 groups x 36 cols
    const int n = t & 15, q = t >> 4;
    for (int cc = 0; cc < 36; ++cc) {
      int col = q * 36 + cc;
      float val;
      if (col < 512) {
        int hh = col >> 7, rem = col & 127, d = rem & 63;
        float hv = hl[n][hh * 64 + d];
        val = (rem < 64) ? sdste[hh][n] * hv : hv;
      } else if (col < 516) val = sdste[col - 512][n];
      else if (col == 516)  val = 1.0f;
      else                  val = 0.0f;
      V8[(size_t)col * NN + nb + n] = f2e4m3(val);
    }
  }
}

// ---------------- Kernel 2: out2[ks] = A8 @ V8 (fp8 MFMA, pure-async staging) ----------------
// tile 96x288, BK=64, grid = cb(2) x ks(nks) x rb(64); nks=6 -> 768 = 3 blocks/CU.
// 4 waves 2x2, wave tile 48x144 (mt3 x nt9). LDS 24 KB. 8B-chunk XOR swizzle (r^(r>>2))&3.
__global__ __launch_bounds__(256, 3) void k2_gemm(
    const unsigned char* __restrict__ A8, const unsigned char* __restrict__ V8,
    float* __restrict__ out2, int nks)
{
  __shared__ unsigned char lA[96 * 64];    // 6,144 B
  __shared__ unsigned char lB[288 * 64];   // 18,432 B
  const int t   = threadIdx.x;
  const int bid = blockIdx.x;
  const int rb  = bid & 63;
  const int tmp = bid >> 6;
  const int ks  = tmp % nks;
  const int cb  = tmp / nks;
  const int krange = NN / nks;
  const int i0 = rb * 96, n0 = cb * 288, k0 = ks * krange;
  const int w = t >> 6, l = t & 63;
  const int wm = w & 1, wn = w >> 1;
  const int lm = l & 15, lk = l >> 4;

  f32x4 acc[3][9];
#pragma unroll
  for (int mt = 0; mt < 3; ++mt)
#pragma unroll
    for (int nt = 0; nt < 9; ++nt) acc[mt][nt] = (f32x4){0.f, 0.f, 0.f, 0.f};

  const int iters = krange / 64;
  for (int it = 0; it < iters; ++it) {
    const int kb = k0 + it * 64;
    const unsigned char* gA = A8 + (size_t)i0 * NN + kb;
    const unsigned char* gB = V8 + (size_t)n0 * NN + kb;
    // Unified staging: 384 A-granules + 1152 B-granules = 1536, 6 per thread.
    // Dest slot gi; source granule chosen so slot d holds k-granule d^s(row).
#pragma unroll
    for (int u = 0; u < 6; ++u) {
      const int gi    = u * 256 + t;
      const int slot0 = u * 256 + (t & ~63);   // wave-uniform LDS base (slot units)
      if (gi < 384) {
        const int row = gi >> 2;
        const int g = (gi & 3) ^ ((row ^ (row >> 2)) & 3);
        async_load16(gA + (size_t)row * NN + g * 16, (char*)lA + (size_t)slot0 * 16);
      } else {
        const int col = (gi - 384) >> 2;
        const int g = (gi & 3) ^ ((col ^ (col >> 2)) & 3);
        async_load16(gB + (size_t)col * NN + g * 16, (char*)lB + (size_t)(slot0 - 384) * 16);
      }
    }
    __syncthreads();
#pragma unroll
    for (int ks2 = 0; ks2 < 2; ++ks2) {
      const int kgo = ks2 * 4 + lk;            // 8B-chunk index 0..7
      long afrag[3];
#pragma unroll
      for (int mt = 0; mt < 3; ++mt) {
        const int rr = wm * 48 + mt * 16 + lm;
        const int sr = (rr ^ (rr >> 2)) & 3;
        afrag[mt] = *(const long*)(lA + rr * 64 + (((kgo >> 1) ^ sr) * 16) + ((kgo & 1) * 8));
      }
#pragma unroll
      for (int nt = 0; nt < 9; ++nt) {
        const int cc = wn * 144 + nt * 16 + lm;
        const int sc = (cc ^ (cc >> 2)) & 3;
        long b = *(const long*)(lB + cc * 64 + (((kgo >> 1) ^ sc) * 16) + ((kgo & 1) * 8));
#pragma unroll
        for (int mt = 0; mt < 3; ++mt)
          acc[mt][nt] = __builtin_amdgcn_mfma_f32_16x16x32_fp8_fp8(afrag[mt], b, acc[mt][nt], 0, 0, 0);
      }
    }
    __syncthreads();
  }

  float* o = out2 + (size_t)ks * ((size_t)NN * NC);
  const int row0 = i0 + wm * 48 + (l >> 4) * 4;
  const int colb = n0 + wn * 144 + (l & 15);
#pragma unroll
  for (int mt = 0; mt < 3; ++mt)
#pragma unroll
    for (int nt = 0; nt < 9; ++nt)
#pragma unroll
      for (int rr = 0; rr < 4; ++rr)
        o[(size_t)(row0 + mt * 16 + rr) * NC + colb + nt * 16] = acc[mt][nt][rr];
}

// ---------------- Kernel 3: combine across nks K-partials ----------------
__global__ __launch_bounds__(256) void k3_final(
    const float* __restrict__ out2, const float* __restrict__ e_src,
    const float* __restrict__ T, float* __restrict__ out, int nks)
{
  const int n = blockIdx.x, c = threadIdx.x;
  const int h = c >> 6, d = c & 63;
  float Se = 0.f, Sp = 0.f, E = 0.f, dg = 0.f;
  for (int s = 0; s < nks; ++s) {
    const float* ra = out2 + (size_t)s * ((size_t)NN * NC) + (size_t)n * NC;
    Se += ra[h * 128 + d];
    Sp += ra[h * 128 + 64 + d];
    E  += ra[512 + h];
    dg += ra[516];
  }
  float e = e_src[h * NN + n];
  float D = e * E + ((float)NN - dg);
  out[(size_t)n * 256 + c] = (e * Se + (T[c] - Sp)) / D;
}

extern "C" void kernel_launch(void* const* d_in, const int* in_sizes, int n_in,
                              void* d_out, int out_size, void* d_ws, size_t ws_size,
                              hipStream_t stream) {
  const float* x  = (const float*)d_in[0];
  const int*   adj= (const int*)d_in[1];
  const float* W  = (const float*)d_in[2];
  const float* Wb = (const float*)d_in[3];
  const float* Aw = (const float*)d_in[4];
  const float* Ab = (const float*)d_in[5];
  float* out = (float*)d_out;
  char* ws = (char*)d_ws;
  unsigned char* V8 = (unsigned char*)ws;               // 3,538,944 B
  float* e_src = (float*)(ws + 3538944);                // 98,304 B
  float* T     = (float*)(ws + 3637248);                // 1,024 B
  unsigned char* A8 = (unsigned char*)(ws + 3638272);   // 37,748,736 B
  float* out2  = (float*)(ws + 41387008);               // nks x 14,155,776 B

  const size_t slab = (size_t)NN * NC * 4;
  const size_t base = 41387008;
  int nks = 2;
  if (ws_size >= base + 6 * slab)      nks = 6;   // grid 768 = 3 blocks/CU
  else if (ws_size >= base + 4 * slab) nks = 4;

  hipLaunchKernelGGL(k0_pack, dim3(2048), dim3(256), 0, stream, adj, A8, T);
  hipLaunchKernelGGL(k1_feat, dim3(384), dim3(256), 0, stream, x, W, Wb, Aw, Ab, V8, e_src, T);
  hipLaunchKernelGGL(k2_gemm, dim3(64 * 2 * nks), dim3(256), 0, stream, A8, V8, out2, nks);
  hipLaunchKernelGGL(k3_final, dim3(NN), dim3(256), 0, stream, out2, e_src, T, out, nks);
}

// Round 6
// 323.826 us; speedup vs baseline: 1.2156x; 1.0522x over previous
//
#include <hip/hip_runtime.h>
#include <stdint.h>

#define NN 6144        // nodes
#define NC 576         // padded V columns (517 used)

typedef float f32x4 __attribute__((ext_vector_type(4)));

// f32 -> OCP e4m3fn, RNE, clamp to +-448
__device__ __forceinline__ unsigned char f2e4m3(float f) {
  unsigned u = __float_as_uint(f);
  unsigned sgn = (u >> 24) & 0x80u;
  unsigned au = u & 0x7FFFFFFFu;
  if (au >= 0x43E00000u) return (unsigned char)(sgn | 0x7E);   // >= 448
  if (au < 0x3C800000u) {                                      // < 2^-6: subnormal
    int q = (int)rintf(__uint_as_float(au) * 512.0f);          // step 2^-9
    return (unsigned char)(sgn | (q >= 8 ? 0x08 : q));
  }
  unsigned r = au + 0x7FFFFu + ((au >> 20) & 1u);              // RNE to 3 mantissa bits
  int e = (int)(r >> 23) - 127;
  unsigned m = (r >> 20) & 7u;
  return (unsigned char)(sgn | ((unsigned)(e + 7) << 3) | m);
}

__device__ __forceinline__ void async_load16(const void* g, void* l) {
  __builtin_amdgcn_global_load_lds(
      (__attribute__((address_space(1))) void*)(uintptr_t)g,
      (__attribute__((address_space(3))) void*)(uint32_t)(uintptr_t)l,
      16, 0, 0);
}

// ---------------- Kernel 01: merged feature pass (blocks 0..383) + adj->fp8 pack (384..1919) ----
__global__ __launch_bounds__(256) void k01(
    const float* __restrict__ x, const float* __restrict__ W,
    const float* __restrict__ Wb, const float* __restrict__ Aw,
    const float* __restrict__ Ab, const int* __restrict__ adj,
    unsigned char* __restrict__ V8, unsigned char* __restrict__ A8,
    float* __restrict__ e_src, float* __restrict__ T)
{
  __shared__ float xs[256][16];
  __shared__ float hl[16][257];
  __shared__ float sdste[4][16];
  const int t = threadIdx.x;

  if (blockIdx.x >= 384) {   // ---- k0-part: adj int32 -> fp8 (0x00 / 0x38) ----
    const size_t total8 = (size_t)NN * NN / 8;   // 8 ints -> 8 bytes
    const int4* a4 = (const int4*)adj;
    uint2* o2 = (uint2*)A8;
    for (size_t g = (size_t)(blockIdx.x - 384) * 256 + t; g < total8;
         g += (size_t)1536 * 256) {
      int4 qa = a4[2 * g], qb = a4[2 * g + 1];
      uint2 p;
      p.x = (unsigned)qa.x * 0x38u | (unsigned)qa.y * 0x3800u |
            (unsigned)qa.z * 0x380000u | (unsigned)qa.w * 0x38000000u;
      p.y = (unsigned)qb.x * 0x38u | (unsigned)qb.y * 0x3800u |
            (unsigned)qb.z * 0x380000u | (unsigned)qb.w * 0x38000000u;
      o2[g] = p;
    }
    return;
  }

  // ---- k1-part: 16 nodes per block (verified R4/R5 structure) ----
  const int nb = blockIdx.x * 16;
  {
    const int n = t >> 4, kq = (t & 15) * 16;
    const float4* xp = (const float4*)(x + (size_t)(nb + n) * 256 + kq);
#pragma unroll
    for (int j = 0; j < 4; ++j) {
      float4 v = xp[j];
      int k = kq + j * 4;
      xs[k][n] = v.x; xs[k+1][n] = v.y; xs[k+2][n] = v.z; xs[k+3][n] = v.w;
    }
  }
  __syncthreads();

  const int cg = t & 31, ng = t >> 5;
  const int c0 = cg * 8, h = c0 >> 6, d0 = c0 & 63;
  const float* wp = W + h * 16384 + d0;
  float acc[2][8];
#pragma unroll
  for (int i = 0; i < 2; ++i)
#pragma unroll
    for (int j = 0; j < 8; ++j) acc[i][j] = 0.f;

#pragma unroll 4
  for (int k = 0; k < 256; ++k) {
    float4 wa = *(const float4*)(wp + (size_t)k * 64);
    float4 wb = *(const float4*)(wp + (size_t)k * 64 + 4);
    float2 xa = *(const float2*)(&xs[k][ng * 2]);
    float xr[2] = {xa.x, xa.y};
    float wr[8] = {wa.x, wa.y, wa.z, wa.w, wb.x, wb.y, wb.z, wb.w};
#pragma unroll
    for (int i = 0; i < 2; ++i)
#pragma unroll
      for (int j = 0; j < 8; ++j) acc[i][j] += xr[i] * wr[j];
  }
#pragma unroll
  for (int i = 0; i < 2; ++i)
#pragma unroll
    for (int j = 0; j < 8; ++j)
      hl[ng * 2 + i][c0 + j] = acc[i][j] + Wb[c0 + j];
  __syncthreads();

  if (t < 64) {
    const int node = t & 15, hd = t >> 4;
    float ss = Ab[hd], sd = 0.f;
#pragma unroll 8
    for (int d = 0; d < 64; ++d) {
      float hv = hl[node][hd * 64 + d];
      ss += hv * Aw[hd * 128 + d];
      sd += hv * Aw[hd * 128 + 64 + d];
    }
    e_src[hd * NN + nb + node] = expf(ss);
    sdste[hd][node] = expf(sd);
  }
  {
    float s = 0.f;
#pragma unroll 8
    for (int n2 = 0; n2 < 16; ++n2) s += hl[n2][t];
    atomicAdd(&T[t], s);
  }
  __syncthreads();

  { // write V column-major fp8: 16 groups x 36 cols
    const int n = t & 15, q = t >> 4;
    for (int cc = 0; cc < 36; ++cc) {
      int col = q * 36 + cc;
      float val;
      if (col < 512) {
        int hh = col >> 7, rem = col & 127, d = rem & 63;
        float hv = hl[n][hh * 64 + d];
        val = (rem < 64) ? sdste[hh][n] * hv : hv;
      } else if (col < 516) val = sdste[col - 512][n];
      else if (col == 516)  val = 1.0f;
      else                  val = 0.0f;
      V8[(size_t)col * NN + nb + n] = f2e4m3(val);
    }
  }
}

// ---------------- Kernel 2: out2[ks] = A8 @ V8, A direct-to-VGPR, B async-LDS ----------------
// tile 192x144, BK=64, 4 waves m-stacked (wave tile 48x144, mt3 x nt9).
// grid = ks(nks) x rb(32) x cb(4); nks=6 -> 768 = 3 blocks/CU. LDS 9 KB (B only).
// k-chunk order kgo = lk*2 + ks2 so each lane's A fragment pair is one contiguous 16B load.
__global__ __launch_bounds__(256, 3) void k2_gemm(
    const unsigned char* __restrict__ A8, const unsigned char* __restrict__ V8,
    float* __restrict__ out2, int nks)
{
  __shared__ unsigned char lB[144 * 64];   // 9,216 B
  const int t   = threadIdx.x;
  const int bid = blockIdx.x;
  const int cb  = bid & 3;
  const int rb  = (bid >> 2) & 31;
  const int ks  = bid >> 7;
  const int krange = NN / nks;
  const int i0 = rb * 192, n0 = cb * 144, k0 = ks * krange;
  const int w = t >> 6, l = t & 63;
  const int lm = l & 15, lk = l >> 4;

  f32x4 acc[3][9];
#pragma unroll
  for (int mt = 0; mt < 3; ++mt)
#pragma unroll
    for (int nt = 0; nt < 9; ++nt) acc[mt][nt] = (f32x4){0.f, 0.f, 0.f, 0.f};

  // A pointer: wave w covers rows i0 + w*48 + mt*16 + lm; lane reads 16B at k-offset lk*16.
  const unsigned char* gA0 = A8 + (size_t)(i0 + w * 48 + lm) * NN + k0 + lk * 16;

  const int iters = krange / 64;
  for (int it = 0; it < iters; ++it) {
    const int kb = k0 + it * 64;
    { // B staging: 144 cols x 64 B = 576 granules; XOR swizzle (col ^ col>>2)&3
      const unsigned char* gB = V8 + (size_t)n0 * NN + kb;
#pragma unroll
      for (int u = 0; u < 2; ++u) {
        const int gi = u * 256 + t;
        const int col = gi >> 2;
        const int g = (gi & 3) ^ ((col ^ (col >> 2)) & 3);
        async_load16(gB + (size_t)col * NN + g * 16,
                     (char*)lB + (size_t)(u * 256 + (t & ~63)) * 16);
      }
      if (t < 64) {
        const int gi = 512 + t;
        const int col = gi >> 2;
        const int g = (gi & 3) ^ ((col ^ (col >> 2)) & 3);
        async_load16(gB + (size_t)col * NN + g * 16, (char*)lB + (size_t)512 * 16);
      }
    }
    // A direct loads (no LDS): 3 x dwordx4 per thread, covers both ks2 chunks
    longlong2 afr[3];
    const unsigned char* gA = gA0 + it * 64;
#pragma unroll
    for (int mt = 0; mt < 3; ++mt)
      afr[mt] = *(const longlong2*)(gA + (size_t)mt * 16 * NN);
    __syncthreads();   // B ready (drains async loads)
#pragma unroll
    for (int ks2 = 0; ks2 < 2; ++ks2) {
#pragma unroll
      for (int nt = 0; nt < 9; ++nt) {
        const int cc = nt * 16 + lm;
        const int sc = (cc ^ (cc >> 2)) & 3;
        long b = *(const long*)(lB + cc * 64 + ((lk ^ sc) * 16) + ks2 * 8);
#pragma unroll
        for (int mt = 0; mt < 3; ++mt)
          acc[mt][nt] = __builtin_amdgcn_mfma_f32_16x16x32_fp8_fp8(
              ks2 ? afr[mt].y : afr[mt].x, b, acc[mt][nt], 0, 0, 0);
      }
    }
    __syncthreads();
  }

  // epilogue: C/D layout col=lm, row=lk*4+rr
  float* o = out2 + (size_t)ks * ((size_t)NN * NC);
  const int row0 = i0 + w * 48 + lk * 4;
  const int colb = n0 + lm;
#pragma unroll
  for (int mt = 0; mt < 3; ++mt)
#pragma unroll
    for (int nt = 0; nt < 9; ++nt)
#pragma unroll
      for (int rr = 0; rr < 4; ++rr)
        o[(size_t)(row0 + mt * 16 + rr) * NC + colb + nt * 16] = acc[mt][nt][rr];
}

// ---------------- Kernel 3: combine across nks K-partials ----------------
__global__ __launch_bounds__(256) void k3_final(
    const float* __restrict__ out2, const float* __restrict__ e_src,
    const float* __restrict__ T, float* __restrict__ out, int nks)
{
  const int n = blockIdx.x, c = threadIdx.x;
  const int h = c >> 6, d = c & 63;
  float Se = 0.f, Sp = 0.f, E = 0.f, dg = 0.f;
  for (int s = 0; s < nks; ++s) {
    const float* ra = out2 + (size_t)s * ((size_t)NN * NC) + (size_t)n * NC;
    Se += ra[h * 128 + d];
    Sp += ra[h * 128 + 64 + d];
    E  += ra[512 + h];
    dg += ra[516];
  }
  float e = e_src[h * NN + n];
  float D = e * E + ((float)NN - dg);
  out[(size_t)n * 256 + c] = (e * Se + (T[c] - Sp)) / D;
}

extern "C" void kernel_launch(void* const* d_in, const int* in_sizes, int n_in,
                              void* d_out, int out_size, void* d_ws, size_t ws_size,
                              hipStream_t stream) {
  const float* x  = (const float*)d_in[0];
  const int*   adj= (const int*)d_in[1];
  const float* W  = (const float*)d_in[2];
  const float* Wb = (const float*)d_in[3];
  const float* Aw = (const float*)d_in[4];
  const float* Ab = (const float*)d_in[5];
  float* out = (float*)d_out;
  char* ws = (char*)d_ws;
  unsigned char* V8 = (unsigned char*)ws;               // 3,538,944 B
  float* e_src = (float*)(ws + 3538944);                // 98,304 B
  float* T     = (float*)(ws + 3637248);                // 1,024 B
  unsigned char* A8 = (unsigned char*)(ws + 3638272);   // 37,748,736 B
  float* out2  = (float*)(ws + 41387008);               // nks x 14,155,776 B

  const size_t slab = (size_t)NN * NC * 4;
  const size_t base = 41387008;
  int nks = 2;
  if (ws_size >= base + 6 * slab)      nks = 6;   // grid 768 = 3 blocks/CU
  else if (ws_size >= base + 4 * slab) nks = 4;

  hipMemsetAsync(T, 0, 1024, stream);
  hipLaunchKernelGGL(k01, dim3(1920), dim3(256), 0, stream,
                     x, W, Wb, Aw, Ab, adj, V8, A8, e_src, T);
  hipLaunchKernelGGL(k2_gemm, dim3(128 * nks), dim3(256), 0, stream, A8, V8, out2, nks);
  hipLaunchKernelGGL(k3_final, dim3(NN), dim3(256), 0, stream, out2, e_src, T, out, nks);
}